// Round 2
// baseline (689.980 us; speedup 1.0000x reference)
//
#include <hip/hip_runtime.h>

#define EPSN 1e-12f
#define SCALE_F 0.044194173824159216f  // 512^-0.5

typedef __bf16 bf16x8 __attribute__((ext_vector_type(8)));
typedef __bf16 bf16x4 __attribute__((ext_vector_type(4)));
typedef float  f32x4  __attribute__((ext_vector_type(4)));

// ---------------- prep: WqT/WkT bf16 [d][c] = W[c][d], LDS tile transpose ----------------
__global__ __launch_bounds__(256) void k_prep_t(const float* __restrict__ Wq,
                                                const float* __restrict__ Wk,
                                                __bf16* __restrict__ WqT,
                                                __bf16* __restrict__ WkT) {
  __shared__ float Tq[32][33], Tk[32][33];
  const int c0 = blockIdx.x * 32, d0 = blockIdx.y * 32;
  const int dx = threadIdx.x, cy = threadIdx.y;  // 32, 8
  #pragma unroll
  for (int p = 0; p < 4; ++p) {
    int c = cy + p * 8;
    Tq[c][dx] = Wq[(size_t)(c0 + c) * 512 + d0 + dx];
    Tk[c][dx] = Wk[(size_t)(c0 + c) * 512 + d0 + dx];
  }
  __syncthreads();
  #pragma unroll
  for (int p = 0; p < 4; ++p) {
    int d = cy + p * 8;
    WqT[(size_t)(d0 + d) * 512 + c0 + dx] = (__bf16)Tq[dx][d];
    WkT[(size_t)(d0 + d) * 512 + c0 + dx] = (__bf16)Tk[dx][d];
  }
}

// ---- prep: WcT[d][kk]: kk<512 -> (Wp@Wf)[kk][d]; kk>=512 -> Wf[kk-512][d]. bpf[d]=bp@Wf+bf
__global__ __launch_bounds__(512) void k_prep_w(const float* __restrict__ Wp,
                                                const float* __restrict__ Wf,
                                                const float* __restrict__ bp,
                                                const float* __restrict__ bfv,
                                                __bf16* __restrict__ WcT,
                                                float* __restrict__ bpf) {
  int kk = blockIdx.x;   // 512
  int d  = threadIdx.x;  // 512
  float a0 = 0.f, a1 = 0.f, a2 = 0.f, a3 = 0.f;
  for (int c = 0; c < 512; c += 4) {
    a0 = fmaf(Wp[kk * 512 + c],     Wf[(size_t)c * 512 + d],         a0);
    a1 = fmaf(Wp[kk * 512 + c + 1], Wf[(size_t)(c + 1) * 512 + d],   a1);
    a2 = fmaf(Wp[kk * 512 + c + 2], Wf[(size_t)(c + 2) * 512 + d],   a2);
    a3 = fmaf(Wp[kk * 512 + c + 3], Wf[(size_t)(c + 3) * 512 + d],   a3);
  }
  WcT[(size_t)d * 1024 + kk]       = (__bf16)((a0 + a1) + (a2 + a3));
  WcT[(size_t)d * 1024 + 512 + kk] = (__bf16)Wf[(size_t)kk * 512 + d];
  if (kk == 0) {
    float b0 = 0.f, b1 = 0.f;
    for (int c = 0; c < 512; c += 2) {
      b0 = fmaf(bp[c],     Wf[(size_t)c * 512 + d],       b0);
      b1 = fmaf(bp[c + 1], Wf[(size_t)(c + 1) * 512 + d], b1);
    }
    bpf[d] = b0 + b1 + bfv[d];
  }
}

// ---------------- fused Q/K GEMM + bias + row l2norm + g ----------------
__global__ __launch_bounds__(512, 2) void k_qk(const float* __restrict__ x,
                                               const __bf16* __restrict__ WqT,
                                               const __bf16* __restrict__ WkT,
                                               const float* __restrict__ bq,
                                               const float* __restrict__ bk,
                                               const float* __restrict__ wg,
                                               __bf16* __restrict__ Qn,
                                               __bf16* __restrict__ Kn,
                                               float* __restrict__ g) {
  __shared__ __bf16 As[2][64][36];
  __shared__ float redQ[8][64], redK[8][64], redG[8][64];
  __shared__ float invq[64], invk[64];
  const int t = threadIdx.x;
  const int lane = t & 63, w = t >> 6;
  const int li = lane & 15, lq = lane >> 4;
  const int n0 = blockIdx.x * 64;
  const int b  = blockIdx.y;
  const int sn = t & 63, sc4 = (t >> 6) * 4;
  const bool nv = (n0 + sn < 784);
  const float* xp = x + ((size_t)b * 512 + sc4) * 784 + n0 + sn;
  const __bf16* wqp = WqT + (size_t)(w * 64 + li) * 512 + lq * 8;
  const __bf16* wkp = WkT + (size_t)(w * 64 + li) * 512 + lq * 8;

  f32x4 accQ[4][4] = {}, accK[4][4] = {};
  bf16x8 bq2[2][4], bk2[2][4];
  float xr[2][4];

  auto issueX = [&](int set, int ks) {
    #pragma unroll
    for (int j = 0; j < 4; ++j)
      xr[set][j] = nv ? xp[(size_t)(ks * 32 + j) * 784] : 0.f;
  };
  auto issueB = [&](int set, int ks) {
    #pragma unroll
    for (int cb = 0; cb < 4; ++cb) {
      bq2[set][cb] = *(const bf16x8*)(wqp + (size_t)cb * 8192 + ks * 32);
      bk2[set][cb] = *(const bf16x8*)(wkp + (size_t)cb * 8192 + ks * 32);
    }
  };
  auto writeA = [&](int buf, int set) {
    bf16x4 v;
    #pragma unroll
    for (int j = 0; j < 4; ++j) v[j] = (__bf16)xr[set][j];
    *(bf16x4*)&As[buf][sn][sc4] = v;
  };

  issueX(0, 0); issueX(1, 1); issueB(0, 0);
  writeA(0, 0);
  __syncthreads();

  #pragma unroll
  for (int ks = 0; ks < 16; ++ks) {
    const int cur = ks & 1, nxt = cur ^ 1;
    if (ks + 2 < 16) issueX(cur, ks + 2);
    if (ks + 1 < 16) issueB(nxt, ks + 1);
    bf16x8 af[4];
    #pragma unroll
    for (int rb = 0; rb < 4; ++rb)
      af[rb] = *(const bf16x8*)&As[cur][rb * 16 + li][lq * 8];
    #pragma unroll
    for (int cb = 0; cb < 4; ++cb)
      #pragma unroll
      for (int rb = 0; rb < 4; ++rb) {
        accQ[rb][cb] = __builtin_amdgcn_mfma_f32_16x16x32_bf16(af[rb], bq2[cur][cb], accQ[rb][cb], 0, 0, 0);
        accK[rb][cb] = __builtin_amdgcn_mfma_f32_16x16x32_bf16(af[rb], bk2[cur][cb], accK[rb][cb], 0, 0, 0);
      }
    if (ks + 1 < 16) writeA(nxt, nxt);
    __syncthreads();
  }

  float bqv[4], bkv[4], wgv[4];
  #pragma unroll
  for (int cb = 0; cb < 4; ++cb) {
    int col = w * 64 + cb * 16 + li;
    bqv[cb] = bq[col]; bkv[cb] = bk[col]; wgv[cb] = wg[col];
  }
  #pragma unroll
  for (int rb = 0; rb < 4; ++rb)
    #pragma unroll
    for (int cb = 0; cb < 4; ++cb)
      #pragma unroll
      for (int j = 0; j < 4; ++j) {
        accQ[rb][cb][j] += bqv[cb];
        accK[rb][cb][j] += bkv[cb];
      }
  #pragma unroll
  for (int rb = 0; rb < 4; ++rb)
    #pragma unroll
    for (int j = 0; j < 4; ++j) {
      float sq = 0.f, sk = 0.f, sg = 0.f;
      #pragma unroll
      for (int cb = 0; cb < 4; ++cb) {
        float vq = accQ[rb][cb][j], vk = accK[rb][cb][j];
        sq = fmaf(vq, vq, sq); sk = fmaf(vk, vk, sk); sg = fmaf(vq, wgv[cb], sg);
      }
      sq += __shfl_xor(sq, 1); sq += __shfl_xor(sq, 2); sq += __shfl_xor(sq, 4); sq += __shfl_xor(sq, 8);
      sk += __shfl_xor(sk, 1); sk += __shfl_xor(sk, 2); sk += __shfl_xor(sk, 4); sk += __shfl_xor(sk, 8);
      sg += __shfl_xor(sg, 1); sg += __shfl_xor(sg, 2); sg += __shfl_xor(sg, 4); sg += __shfl_xor(sg, 8);
      if (li == 0) {
        int row = rb * 16 + lq * 4 + j;
        redQ[w][row] = sq; redK[w][row] = sk; redG[w][row] = sg;
      }
    }
  __syncthreads();
  if (t < 64) {
    float sq = 0.f, sk = 0.f, sg = 0.f;
    #pragma unroll
    for (int wv = 0; wv < 8; ++wv) { sq += redQ[wv][t]; sk += redK[wv][t]; sg += redG[wv][t]; }
    float iq = 1.f / fmaxf(sqrtf(sq), EPSN);
    float ik = 1.f / fmaxf(sqrtf(sk), EPSN);
    invq[t] = iq; invk[t] = ik;
    if (n0 + t < 784) g[(size_t)b * 784 + n0 + t] = sg * iq;
  }
  __syncthreads();
  #pragma unroll
  for (int rb = 0; rb < 4; ++rb)
    #pragma unroll
    for (int j = 0; j < 4; ++j) {
      int row = rb * 16 + lq * 4 + j;
      if (n0 + row < 784) {
        float iq = invq[row], ik = invk[row];
        size_t base = ((size_t)b * 784 + n0 + row) * 512 + w * 64 + li;
        #pragma unroll
        for (int cb = 0; cb < 4; ++cb) {
          Qn[base + cb * 16] = (__bf16)(accQ[rb][cb][j] * iq);
          Kn[base + cb * 16] = (__bf16)(accK[rb][cb][j] * ik);
        }
      }
    }
}

// ---------------- ctx partials ----------------
__global__ __launch_bounds__(512) void k_ctx1(const __bf16* __restrict__ Qn,
                                              const float* __restrict__ g,
                                              float* __restrict__ pctx,
                                              float* __restrict__ pgsq) {
  const int cx = blockIdx.x;
  const int b  = blockIdx.y;
  const int t  = threadIdx.x;
  const int nbase = cx * 112;
  __shared__ float wred[8];
  const float* gb = g + (size_t)b * 784 + nbase;
  float s = 0.f;
  if (t < 112) { float v = gb[t]; s = v * v; }
  s += __shfl_xor(s, 1);  s += __shfl_xor(s, 2);  s += __shfl_xor(s, 4);
  s += __shfl_xor(s, 8);  s += __shfl_xor(s, 16); s += __shfl_xor(s, 32);
  if ((t & 63) == 0) wred[t >> 6] = s;
  __syncthreads();
  if (t == 0) {
    float tot = 0.f;
    #pragma unroll
    for (int i = 0; i < 8; ++i) tot += wred[i];
    pgsq[b * 7 + cx] = tot;
  }
  const __bf16* qb = Qn + ((size_t)b * 784 + nbase) * 512 + t;
  float a0 = 0.f, a1 = 0.f, a2 = 0.f, a3 = 0.f;
  for (int n = 0; n < 112; n += 4) {
    a0 = fmaf(gb[n],     (float)qb[(size_t)n * 512],       a0);
    a1 = fmaf(gb[n + 1], (float)qb[(size_t)(n + 1) * 512], a1);
    a2 = fmaf(gb[n + 2], (float)qb[(size_t)(n + 2) * 512], a2);
    a3 = fmaf(gb[n + 3], (float)qb[(size_t)(n + 3) * 512], a3);
  }
  pctx[((size_t)b * 7 + cx) * 512 + t] = (a0 + a1) + (a2 + a3);
}

__global__ __launch_bounds__(512) void k_ctx2(const float* __restrict__ pctx,
                                              const float* __restrict__ pgsq,
                                              float* __restrict__ ctx) {
  const int b = blockIdx.x, t = threadIdx.x;
  float tot = 0.f;
  #pragma unroll
  for (int i = 0; i < 7; ++i) tot += pgsq[b * 7 + i];
  float alpha = SCALE_F / fmaxf(sqrtf(tot) * SCALE_F, EPSN);
  float s = 0.f;
  #pragma unroll
  for (int i = 0; i < 7; ++i) s += pctx[((size_t)b * 7 + i) * 512 + t];
  ctx[(size_t)b * 512 + t] = alpha * s;
}

// ---------------- final GEMM ----------------
__global__ __launch_bounds__(512) void k_out(const __bf16* __restrict__ Qn,
                                             const __bf16* __restrict__ Kn,
                                             const float* __restrict__ ctx,
                                             const __bf16* __restrict__ WcT,
                                             const float* __restrict__ bpf,
                                             float* __restrict__ out) {
  __shared__ __align__(16) char smem[(2 * 64 * 36 + 2 * 256 * 36) * 2];
  __bf16 (*As)[64][36]  = (__bf16(*)[64][36])smem;
  __bf16 (*Bs)[256][36] = (__bf16(*)[256][36])(smem + 2 * 64 * 36 * 2);
  float  (*Cs)[65]      = (float(*)[65])smem;
  const int t = threadIdx.x;
  const int lane = t & 63, w = t >> 6;
  const int li = lane & 15, lq = lane >> 4;
  const int wr = w >> 2, wc = w & 3;
  const int n0 = blockIdx.x * 64;
  const int d0 = blockIdx.y * 256;
  const int b  = blockIdx.z;
  const int an = t & 63, ak4 = (t >> 6) * 4;
  const bool anv = (n0 + an < 784);
  const __bf16* qrow = Qn + ((size_t)b * 784 + n0 + an) * 512;
  const __bf16* krow = Kn + ((size_t)b * 784 + n0 + an) * 512;
  const float* cxp = ctx + (size_t)b * 512;
  const int br = t >> 2, bc8 = (t & 3) * 8;
  const __bf16* wp0 = WcT + (size_t)(d0 + br) * 1024 + bc8;
  const __bf16* wp1 = WcT + (size_t)(d0 + br + 128) * 1024 + bc8;

  f32x4 acc[2][4] = {};
  bf16x4 aqk[2];
  f32x4 cx4[2];
  bf16x8 bw[2][2];

  auto issueA = [&](int set, int ks) {
    int kk = ks * 32 + ak4;
    bf16x4 v = {};
    if (ks < 16) {
      if (anv) v = *(const bf16x4*)(krow + kk);
      cx4[set] = *(const f32x4*)(cxp + kk);
    } else {
      if (anv) v = *(const bf16x4*)(qrow + kk - 512);
    }
    aqk[set] = v;
  };
  auto issueB = [&](int set, int ks) {
    bw[set][0] = *(const bf16x8*)(wp0 + ks * 32);
    bw[set][1] = *(const bf16x8*)(wp1 + ks * 32);
  };
  auto writeAB = [&](int buf, int set, int ks) {
    bf16x4 v;
    if (ks < 16) {
      #pragma unroll
      for (int j = 0; j < 4; ++j) v[j] = (__bf16)((float)aqk[set][j] * cx4[set][j]);
    } else {
      v = aqk[set];
    }
    *(bf16x4*)&As[buf][an][ak4] = v;
    *(bf16x8*)&Bs[buf][br][bc8]       = bw[set][0];
    *(bf16x8*)&Bs[buf][br + 128][bc8] = bw[set][1];
  };

  issueA(0, 0); issueB(0, 0); issueA(1, 1); issueB(1, 1);
  writeAB(0, 0, 0);
  __syncthreads();

  #pragma unroll
  for (int ks = 0; ks < 32; ++ks) {
    const int cur = ks & 1, nxt = cur ^ 1;
    if (ks + 2 < 32) { issueA(cur, ks + 2); issueB(cur, ks + 2); }
    bf16x8 af[2], bf[4];
    #pragma unroll
    for (int rb = 0; rb < 2; ++rb)
      af[rb] = *(const bf16x8*)&As[cur][wr * 32 + rb * 16 + li][lq * 8];
    #pragma unroll
    for (int cb = 0; cb < 4; ++cb)
      bf[cb] = *(const bf16x8*)&Bs[cur][wc * 64 + cb * 16 + li][lq * 8];
    #pragma unroll
    for (int cb = 0; cb < 4; ++cb)
      #pragma unroll
      for (int rb = 0; rb < 2; ++rb)
        acc[rb][cb] = __builtin_amdgcn_mfma_f32_16x16x32_bf16(af[rb], bf[cb], acc[rb][cb], 0, 0, 0);
    if (ks + 1 < 32) writeAB(nxt, nxt, ks + 1);
    __syncthreads();
  }

  for (int ch = 0; ch < 4; ++ch) {
    if (wc == ch) {
      #pragma unroll
      for (int cb = 0; cb < 4; ++cb) {
        int colL = cb * 16 + li;
        float bias = bpf[d0 + ch * 64 + colL];
        #pragma unroll
        for (int rb = 0; rb < 2; ++rb)
          #pragma unroll
          for (int j = 0; j < 4; ++j)
            Cs[colL][wr * 32 + rb * 16 + lq * 4 + j] = acc[rb][cb][j] + bias;
      }
    }
    __syncthreads();
    {
      int n = t & 63, dl = t >> 6;
      if (n0 + n < 784) {
        #pragma unroll
        for (int p = 0; p < 8; ++p)
          out[((size_t)b * 512 + d0 + ch * 64 + dl + p * 8) * 784 + n0 + n] = Cs[dl + p * 8][n];
      }
    }
    __syncthreads();
  }
}

extern "C" void kernel_launch(void* const* d_in, const int* in_sizes, int n_in,
                              void* d_out, int out_size, void* d_ws, size_t ws_size,
                              hipStream_t stream) {
  const float* x   = (const float*)d_in[0];
  const float* Wq  = (const float*)d_in[1];
  const float* bq  = (const float*)d_in[2];
  const float* Wk  = (const float*)d_in[3];
  const float* bk  = (const float*)d_in[4];
  const float* wg  = (const float*)d_in[5];
  const float* Wp  = (const float*)d_in[6];
  const float* bp  = (const float*)d_in[7];
  const float* Wf  = (const float*)d_in[8];
  const float* bfv = (const float*)d_in[9];
  float* out = (float*)d_out;
  char* ws = (char*)d_ws;

  const size_t SZQN = (size_t)64 * 784 * 512 * 2;
  __bf16* Qn   = (__bf16*)(ws);
  __bf16* Kn   = (__bf16*)(ws + SZQN);
  __bf16* WqT  = (__bf16*)(ws + 2 * SZQN);
  __bf16* WkT  = (__bf16*)(ws + 2 * SZQN + 524288);
  __bf16* WcT  = (__bf16*)(ws + 2 * SZQN + 2 * 524288);
  float*  gbuf = (float*) (ws + 2 * SZQN + 2 * 524288 + 1048576);
  float*  ctx  = (float*) (ws + 2 * SZQN + 2 * 524288 + 1048576 + 200704);
  float*  bpf  = (float*) (ws + 2 * SZQN + 2 * 524288 + 1048576 + 200704 + 131072);
  float*  pctx = (float*)(ws + 2 * SZQN);              // aliases WqT/WkT (dead after k_qk)
  float*  pgsq = (float*)(ws + 2 * SZQN + 917504);

  k_prep_t<<<dim3(16, 16),    dim3(32, 8), 0, stream>>>(Wq, Wk, WqT, WkT);
  k_prep_w<<<dim3(512),       dim3(512),   0, stream>>>(Wp, Wf, bp, bfv, WcT, bpf);
  k_qk    <<<dim3(13, 64),    dim3(512),   0, stream>>>(x, WqT, WkT, bq, bk, wg, Qn, Kn, gbuf);
  k_ctx1  <<<dim3(7, 64),     dim3(512),   0, stream>>>(Qn, gbuf, pctx, pgsq);
  k_ctx2  <<<dim3(64),        dim3(512),   0, stream>>>(pctx, pgsq, ctx);
  k_out   <<<dim3(13, 2, 64), dim3(512),   0, stream>>>(Qn, Kn, ctx, WcT, bpf, out);
}

// Round 3
// 400.573 us; speedup vs baseline: 1.7225x; 1.7225x over previous
//
#include <hip/hip_runtime.h>

#define EPSN 1e-12f
#define SCALE_F 0.044194173824159216f  // 512^-0.5

typedef __bf16 bf16x8 __attribute__((ext_vector_type(8)));
typedef __bf16 bf16x4 __attribute__((ext_vector_type(4)));
typedef float  f32x4  __attribute__((ext_vector_type(4)));

// ---------------- prep: WqT/WkT bf16 [d][c] = W[c][d], LDS tile transpose ----------------
__global__ __launch_bounds__(256) void k_prep_t(const float* __restrict__ Wq,
                                                const float* __restrict__ Wk,
                                                __bf16* __restrict__ WqT,
                                                __bf16* __restrict__ WkT) {
  __shared__ float Tq[32][33], Tk[32][33];
  const int c0 = blockIdx.x * 32, d0 = blockIdx.y * 32;
  const int dx = threadIdx.x, cy = threadIdx.y;  // 32, 8
  #pragma unroll
  for (int p = 0; p < 4; ++p) {
    int c = cy + p * 8;
    Tq[c][dx] = Wq[(size_t)(c0 + c) * 512 + d0 + dx];
    Tk[c][dx] = Wk[(size_t)(c0 + c) * 512 + d0 + dx];
  }
  __syncthreads();
  #pragma unroll
  for (int p = 0; p < 4; ++p) {
    int d = cy + p * 8;
    WqT[(size_t)(d0 + d) * 512 + c0 + dx] = (__bf16)Tq[dx][d];
    WkT[(size_t)(d0 + d) * 512 + c0 + dx] = (__bf16)Tk[dx][d];
  }
}

// ---- prep: WcT[d][kk]: kk<512 -> (Wp@Wf)[kk][d]; kk>=512 -> Wf[kk-512][d]. bpf[d]=bp@Wf+bf
__global__ __launch_bounds__(512) void k_prep_w(const float* __restrict__ Wp,
                                                const float* __restrict__ Wf,
                                                const float* __restrict__ bp,
                                                const float* __restrict__ bfv,
                                                __bf16* __restrict__ WcT,
                                                float* __restrict__ bpf) {
  int kk = blockIdx.x;   // 512
  int d  = threadIdx.x;  // 512
  float a0 = 0.f, a1 = 0.f, a2 = 0.f, a3 = 0.f;
  for (int c = 0; c < 512; c += 4) {
    a0 = fmaf(Wp[kk * 512 + c],     Wf[(size_t)c * 512 + d],         a0);
    a1 = fmaf(Wp[kk * 512 + c + 1], Wf[(size_t)(c + 1) * 512 + d],   a1);
    a2 = fmaf(Wp[kk * 512 + c + 2], Wf[(size_t)(c + 2) * 512 + d],   a2);
    a3 = fmaf(Wp[kk * 512 + c + 3], Wf[(size_t)(c + 3) * 512 + d],   a3);
  }
  WcT[(size_t)d * 1024 + kk]       = (__bf16)((a0 + a1) + (a2 + a3));
  WcT[(size_t)d * 1024 + 512 + kk] = (__bf16)Wf[(size_t)kk * 512 + d];
  if (kk == 0) {
    float b0 = 0.f, b1 = 0.f;
    for (int c = 0; c < 512; c += 2) {
      b0 = fmaf(bp[c],     Wf[(size_t)c * 512 + d],       b0);
      b1 = fmaf(bp[c + 1], Wf[(size_t)(c + 1) * 512 + d], b1);
    }
    bpf[d] = b0 + b1 + bfv[d];
  }
}

// ---------------- Q or K GEMM + bias + row l2norm (+ g for Q) ----------------
// blockIdx.z: 0=Q, 1=K. Tile 64 tokens x 512 d, 8 waves, wave w -> cols w*64.
// acc 4x4 frags = 64 f32/lane. Static double-buffered pipeline, one barrier/step.
__global__ __launch_bounds__(512) void k_qk(const float* __restrict__ x,
                                            const __bf16* __restrict__ WqT,
                                            const __bf16* __restrict__ WkT,
                                            const float* __restrict__ bq,
                                            const float* __restrict__ bk,
                                            const float* __restrict__ wg,
                                            __bf16* __restrict__ Qn,
                                            __bf16* __restrict__ Kn,
                                            float* __restrict__ g) {
  __shared__ __bf16 As0[64][40], As1[64][40];
  __shared__ float red[8][64], redG[8][64];
  __shared__ float invv[64];
  const int t = threadIdx.x;
  const int lane = t & 63, w = t >> 6;
  const int li = lane & 15, lq = lane >> 4;
  const int n0 = blockIdx.x * 64;
  const int b  = blockIdx.y;
  const int isK = blockIdx.z;
  const __bf16* Wt  = isK ? WkT : WqT;
  const float* bias = isK ? bk : bq;
  __bf16* dst       = isK ? Kn : Qn;
  const int sn = t & 63, sc4 = (t >> 6) * 4;
  const bool nv = (n0 + sn < 784);
  const float* xp = x + ((size_t)b * 512 + sc4) * 784 + n0 + sn;
  const __bf16* wp = Wt + (size_t)(w * 64 + li) * 512 + lq * 8;

  f32x4 acc[4][4] = {};
  bf16x8 bA[4], bB[4];
  float xA[4], xB[4];

  auto issueX = [&](float (&xr)[4], int ks) {
    #pragma unroll
    for (int j = 0; j < 4; ++j)
      xr[j] = nv ? xp[(size_t)(ks * 32 + j) * 784] : 0.f;
  };
  auto issueB = [&](bf16x8 (&bb)[4], int ks) {
    #pragma unroll
    for (int cb = 0; cb < 4; ++cb)
      bb[cb] = *(const bf16x8*)(wp + (size_t)cb * 8192 + ks * 32);
  };
  auto writeA = [&](__bf16 (*Asb)[40], const float (&xr)[4]) {
    bf16x4 v;
    #pragma unroll
    for (int j = 0; j < 4; ++j) v[j] = (__bf16)xr[j];
    *(bf16x4*)&Asb[sn][sc4] = v;
  };
  auto step = [&](const __bf16 (*Asb)[40], const bf16x8 (&bb)[4]) {
    bf16x8 af[4];
    #pragma unroll
    for (int rb = 0; rb < 4; ++rb)
      af[rb] = *(const bf16x8*)&Asb[rb * 16 + li][lq * 8];
    #pragma unroll
    for (int cb = 0; cb < 4; ++cb)
      #pragma unroll
      for (int rb = 0; rb < 4; ++rb)
        acc[rb][cb] = __builtin_amdgcn_mfma_f32_16x16x32_bf16(af[rb], bb[cb], acc[rb][cb], 0, 0, 0);
  };

  issueX(xA, 0); issueX(xB, 1); issueB(bA, 0);
  writeA(As0, xA);
  __syncthreads();

  #pragma unroll 1
  for (int ks = 0; ks < 14; ks += 2) {
    issueX(xA, ks + 2);
    issueB(bB, ks + 1);
    step(As0, bA);
    writeA(As1, xB);
    __syncthreads();
    issueX(xB, ks + 3);
    issueB(bA, ks + 2);
    step(As1, bB);
    writeA(As0, xA);
    __syncthreads();
  }
  issueB(bB, 15);
  step(As0, bA);
  writeA(As1, xB);
  __syncthreads();
  step(As1, bB);

  // epilogue: + bias, row sumsq (and g-dot for Q), normalize, store bf16
  float bv[4], wv[4];
  #pragma unroll
  for (int cb = 0; cb < 4; ++cb) {
    int col = w * 64 + cb * 16 + li;
    bv[cb] = bias[col];
    wv[cb] = isK ? 0.f : wg[col];
  }
  #pragma unroll
  for (int rb = 0; rb < 4; ++rb)
    #pragma unroll
    for (int cb = 0; cb < 4; ++cb)
      #pragma unroll
      for (int j = 0; j < 4; ++j)
        acc[rb][cb][j] += bv[cb];
  #pragma unroll
  for (int rb = 0; rb < 4; ++rb)
    #pragma unroll
    for (int j = 0; j < 4; ++j) {
      float ss = 0.f, sg = 0.f;
      #pragma unroll
      for (int cb = 0; cb < 4; ++cb) {
        float v = acc[rb][cb][j];
        ss = fmaf(v, v, ss); sg = fmaf(v, wv[cb], sg);
      }
      ss += __shfl_xor(ss, 1); ss += __shfl_xor(ss, 2); ss += __shfl_xor(ss, 4); ss += __shfl_xor(ss, 8);
      sg += __shfl_xor(sg, 1); sg += __shfl_xor(sg, 2); sg += __shfl_xor(sg, 4); sg += __shfl_xor(sg, 8);
      if (li == 0) {
        int row = rb * 16 + lq * 4 + j;
        red[w][row] = ss; redG[w][row] = sg;
      }
    }
  __syncthreads();
  if (t < 64) {
    float ss = 0.f, sg = 0.f;
    #pragma unroll
    for (int wv2 = 0; wv2 < 8; ++wv2) { ss += red[wv2][t]; sg += redG[wv2][t]; }
    float iv = 1.f / fmaxf(sqrtf(ss), EPSN);
    invv[t] = iv;
    if (!isK && (n0 + t < 784)) g[(size_t)b * 784 + n0 + t] = sg * iv;
  }
  __syncthreads();
  #pragma unroll
  for (int rb = 0; rb < 4; ++rb)
    #pragma unroll
    for (int j = 0; j < 4; ++j) {
      int row = rb * 16 + lq * 4 + j;
      if (n0 + row < 784) {
        float iv = invv[row];
        size_t base = ((size_t)b * 784 + n0 + row) * 512 + w * 64 + li;
        #pragma unroll
        for (int cb = 0; cb < 4; ++cb)
          dst[base + cb * 16] = (__bf16)(acc[rb][cb][j] * iv);
      }
    }
}

// ---------------- ctx partials ----------------
__global__ __launch_bounds__(512) void k_ctx1(const __bf16* __restrict__ Qn,
                                              const float* __restrict__ g,
                                              float* __restrict__ pctx,
                                              float* __restrict__ pgsq) {
  const int cx = blockIdx.x;
  const int b  = blockIdx.y;
  const int t  = threadIdx.x;
  const int nbase = cx * 112;
  __shared__ float wred[8];
  const float* gb = g + (size_t)b * 784 + nbase;
  float s = 0.f;
  if (t < 112) { float v = gb[t]; s = v * v; }
  s += __shfl_xor(s, 1);  s += __shfl_xor(s, 2);  s += __shfl_xor(s, 4);
  s += __shfl_xor(s, 8);  s += __shfl_xor(s, 16); s += __shfl_xor(s, 32);
  if ((t & 63) == 0) wred[t >> 6] = s;
  __syncthreads();
  if (t == 0) {
    float tot = 0.f;
    #pragma unroll
    for (int i = 0; i < 8; ++i) tot += wred[i];
    pgsq[b * 7 + cx] = tot;
  }
  const __bf16* qb = Qn + ((size_t)b * 784 + nbase) * 512 + t;
  float a0 = 0.f, a1 = 0.f, a2 = 0.f, a3 = 0.f;
  for (int n = 0; n < 112; n += 4) {
    a0 = fmaf(gb[n],     (float)qb[(size_t)n * 512],       a0);
    a1 = fmaf(gb[n + 1], (float)qb[(size_t)(n + 1) * 512], a1);
    a2 = fmaf(gb[n + 2], (float)qb[(size_t)(n + 2) * 512], a2);
    a3 = fmaf(gb[n + 3], (float)qb[(size_t)(n + 3) * 512], a3);
  }
  pctx[((size_t)b * 7 + cx) * 512 + t] = (a0 + a1) + (a2 + a3);
}

__global__ __launch_bounds__(512) void k_ctx2(const float* __restrict__ pctx,
                                              const float* __restrict__ pgsq,
                                              float* __restrict__ ctx) {
  const int b = blockIdx.x, t = threadIdx.x;
  float tot = 0.f;
  #pragma unroll
  for (int i = 0; i < 7; ++i) tot += pgsq[b * 7 + i];
  float alpha = SCALE_F / fmaxf(sqrtf(tot) * SCALE_F, EPSN);
  float s = 0.f;
  #pragma unroll
  for (int i = 0; i < 7; ++i) s += pctx[((size_t)b * 7 + i) * 512 + t];
  ctx[(size_t)b * 512 + t] = alpha * s;
}

// ---------------- final GEMM: out[b,d,n] = ([ctx*Kn | Qn] @ [Wpf;Wf] + bpf)^T ----------------
// Tile 64 tokens x 512 d (all d -> Qn/Kn read once), K=1024, BK=32.
// 8 waves, wave w -> cols w*64, acc 4x4. B register-direct from L2 (no B LDS).
// Epilogue: direct f32x4 stores; lanes (li,lq) tile contiguous 64B segments of out[d][n].
__global__ __launch_bounds__(512) void k_out(const __bf16* __restrict__ Qn,
                                             const __bf16* __restrict__ Kn,
                                             const float* __restrict__ ctx,
                                             const __bf16* __restrict__ WcT,
                                             const float* __restrict__ bpf,
                                             float* __restrict__ out) {
  __shared__ __bf16 As0[64][40], As1[64][40];
  const int t = threadIdx.x;
  const int lane = t & 63, w = t >> 6;
  const int li = lane & 15, lq = lane >> 4;
  const int n0 = blockIdx.x * 64;
  const int b  = blockIdx.y;
  const int an = t & 63, ak4 = (t >> 6) * 4;
  const bool anv = (n0 + an < 784);
  const __bf16* qrow = Qn + ((size_t)b * 784 + n0 + an) * 512;
  const __bf16* krow = Kn + ((size_t)b * 784 + n0 + an) * 512;
  const float* cxp = ctx + (size_t)b * 512;
  const __bf16* wp = WcT + (size_t)(w * 64 + li) * 1024 + lq * 8;

  f32x4 acc[4][4] = {};
  bf16x8 bA[4], bB[4];
  bf16x4 aA, aB;
  f32x4 cA, cB;

  auto issueA = [&](bf16x4& aq, f32x4& cx, int ks) {
    int kk = ks * 32 + ak4;
    bf16x4 v = {};
    if (ks < 16) {
      if (anv) v = *(const bf16x4*)(krow + kk);
      cx = *(const f32x4*)(cxp + kk);
    } else {
      if (anv) v = *(const bf16x4*)(qrow + kk - 512);
    }
    aq = v;
  };
  auto issueB = [&](bf16x8 (&bb)[4], int ks) {
    #pragma unroll
    for (int cb = 0; cb < 4; ++cb)
      bb[cb] = *(const bf16x8*)(wp + (size_t)cb * 16384 + ks * 32);
  };
  auto writeA = [&](__bf16 (*Asb)[40], bf16x4 aq, f32x4 cx, int ks) {
    bf16x4 v;
    if (ks < 16) {
      #pragma unroll
      for (int j = 0; j < 4; ++j) v[j] = (__bf16)((float)aq[j] * cx[j]);
    } else {
      v = aq;
    }
    *(bf16x4*)&Asb[an][ak4] = v;
  };
  auto step = [&](const __bf16 (*Asb)[40], const bf16x8 (&bb)[4]) {
    bf16x8 af[4];
    #pragma unroll
    for (int rb = 0; rb < 4; ++rb)
      af[rb] = *(const bf16x8*)&Asb[rb * 16 + li][lq * 8];
    #pragma unroll
    for (int cb = 0; cb < 4; ++cb)
      #pragma unroll
      for (int rb = 0; rb < 4; ++rb)
        acc[rb][cb] = __builtin_amdgcn_mfma_f32_16x16x32_bf16(af[rb], bb[cb], acc[rb][cb], 0, 0, 0);
  };

  issueA(aA, cA, 0); issueA(aB, cB, 1); issueB(bA, 0);
  writeA(As0, aA, cA, 0);
  __syncthreads();

  #pragma unroll 1
  for (int ks = 0; ks < 30; ks += 2) {
    issueA(aA, cA, ks + 2);
    issueB(bB, ks + 1);
    step(As0, bA);
    writeA(As1, aB, cB, ks + 1);
    __syncthreads();
    issueA(aB, cB, ks + 3);
    issueB(bA, ks + 2);
    step(As1, bB);
    writeA(As0, aA, cA, ks + 2);
    __syncthreads();
  }
  issueB(bB, 31);
  step(As0, bA);
  writeA(As1, aB, cB, 31);
  __syncthreads();
  step(As1, bB);

  // epilogue: + bias, direct stores. lane holds 4 consecutive n for d = w*64+cb*16+li.
  float bv[4];
  #pragma unroll
  for (int cb = 0; cb < 4; ++cb) bv[cb] = bpf[w * 64 + cb * 16 + li];
  #pragma unroll
  for (int rb = 0; rb < 4; ++rb) {
    int nrow = n0 + rb * 16 + lq * 4;
    if (nrow < 784) {
      #pragma unroll
      for (int cb = 0; cb < 4; ++cb) {
        f32x4 v;
        #pragma unroll
        for (int j = 0; j < 4; ++j) v[j] = acc[rb][cb][j] + bv[cb];
        *(f32x4*)&out[((size_t)b * 512 + w * 64 + cb * 16 + li) * 784 + nrow] = v;
      }
    }
  }
}

extern "C" void kernel_launch(void* const* d_in, const int* in_sizes, int n_in,
                              void* d_out, int out_size, void* d_ws, size_t ws_size,
                              hipStream_t stream) {
  const float* x   = (const float*)d_in[0];
  const float* Wq  = (const float*)d_in[1];
  const float* bq  = (const float*)d_in[2];
  const float* Wk  = (const float*)d_in[3];
  const float* bk  = (const float*)d_in[4];
  const float* wg  = (const float*)d_in[5];
  const float* Wp  = (const float*)d_in[6];
  const float* bp  = (const float*)d_in[7];
  const float* Wf  = (const float*)d_in[8];
  const float* bfv = (const float*)d_in[9];
  float* out = (float*)d_out;
  char* ws = (char*)d_ws;

  const size_t SZQN = (size_t)64 * 784 * 512 * 2;
  __bf16* Qn   = (__bf16*)(ws);
  __bf16* Kn   = (__bf16*)(ws + SZQN);
  __bf16* WqT  = (__bf16*)(ws + 2 * SZQN);
  __bf16* WkT  = (__bf16*)(ws + 2 * SZQN + 524288);
  __bf16* WcT  = (__bf16*)(ws + 2 * SZQN + 2 * 524288);
  float*  gbuf = (float*) (ws + 2 * SZQN + 2 * 524288 + 1048576);
  float*  ctx  = (float*) (ws + 2 * SZQN + 2 * 524288 + 1048576 + 200704);
  float*  bpf  = (float*) (ws + 2 * SZQN + 2 * 524288 + 1048576 + 200704 + 131072);
  float*  pctx = (float*)(ws + 2 * SZQN);              // aliases WqT/WkT (dead after k_qk)
  float*  pgsq = (float*)(ws + 2 * SZQN + 917504);

  k_prep_t<<<dim3(16, 16),    dim3(32, 8), 0, stream>>>(Wq, Wk, WqT, WkT);
  k_prep_w<<<dim3(512),       dim3(512),   0, stream>>>(Wp, Wf, bp, bfv, WcT, bpf);
  k_qk    <<<dim3(13, 64, 2), dim3(512),   0, stream>>>(x, WqT, WkT, bq, bk, wg, Qn, Kn, gbuf);
  k_ctx1  <<<dim3(7, 64),     dim3(512),   0, stream>>>(Qn, gbuf, pctx, pgsq);
  k_ctx2  <<<dim3(64),        dim3(512),   0, stream>>>(pctx, pgsq, ctx);
  k_out   <<<dim3(13, 64),    dim3(512),   0, stream>>>(Qn, Kn, ctx, WcT, bpf, out);
}